// Round 9
// baseline (498.675 us; speedup 1.0000x reference)
//
#include <hip/hip_runtime.h>
#include <math.h>

// Problem constants
#define NPTS   131072          // 32*64*64 points
#define DIMS   64              // embedding dim / channels
#define KCODES 512             // codebook size
#define HW     4096            // 64*64 spatial

// d_out flat offsets (floats), reference tuple order:
// (loss, quantized_out[NCHW], perplexity, encodings, quantized_flat)
#define OFF_LOSS 0
#define OFF_QOUT 1
#define OFF_PERP 8388609
#define OFF_ENC  8388610
#define OFF_QF   75497474   // 8388610 + 67108864

// d_ws byte offsets (total 137216 <= proven 143360 footprint)
#define WS_HIST  0          // unsigned[512] (zeroed by vq_prep)
#define WS_NRM   2048       // float[512]
#define WS_EH    4096       // ushort[512*64] bf16 hi, MFMA-fragment order
#define WS_EL    69632      // ushort[512*64] bf16 lo, MFMA-fragment order
#define WS_BLOSS 135168     // float[512] atomic loss bins (zeroed by vq_prep)

// split-bf16 distance error <~2.4e-4; pairwise comparison error <4.8e-4.
// margin 2e-3 still flags every possible argmin flip (4x cushion).
#define EPS_MARGIN 2e-3f

typedef __attribute__((ext_vector_type(8))) short short8;
typedef __attribute__((ext_vector_type(4))) float f32x4;

__device__ __forceinline__ unsigned short f2bf(float f) {
    unsigned u = __float_as_uint(f);
    unsigned r = (u + 0x7fffu + ((u >> 16) & 1u)) >> 16;   // RNE
    return (unsigned short)r;
}
__device__ __forceinline__ float bf2f(unsigned short h) {
    return __uint_as_float(((unsigned)h) << 16);
}

// ---------------------------------------------------------------------------
// Prep: split codebook into bf16 hi/lo in MFMA B-fragment order:
//   idx = ((t*2 + s)*64 + quad*16 + col)*8 + j,  k = t*16+col, d = s*32+quad*8+j
// so vq_fused's lane l loads short8 at [(t*2+s)*64 + l] -> fully coalesced.
// Also zeroes hist and the atomic loss bins.
// ---------------------------------------------------------------------------
__global__ void vq_prep(const float* __restrict__ emb,
                        unsigned short* __restrict__ ehF,
                        unsigned short* __restrict__ elF,
                        float* __restrict__ nrm,
                        unsigned* __restrict__ hist,
                        float* __restrict__ bloss)
{
    int k = blockIdx.x;      // 512
    int d = threadIdx.x;     // 64
    float v = emb[k * DIMS + d];
    unsigned short h = f2bf(v);
    int t = k >> 4, col = k & 15;
    int s = d >> 5, quad = (d >> 3) & 3, j = d & 7;
    int idx = (((t * 2 + s) * 64) + quad * 16 + col) * 8 + j;
    ehF[idx] = h;
    elF[idx] = f2bf(v - bf2f(h));
    double sq = (double)v * (double)v;
    #pragma unroll
    for (int off = 32; off > 0; off >>= 1)
        sq += __shfl_down(sq, off, 64);
    if (d == 0) { nrm[k] = (float)sq; hist[k] = 0u; bloss[k] = 0.f; }
}

// ---------------------------------------------------------------------------
// ROUND-8/9: SINGLE-WAVE BLOCKS. Evidence ledger: five scan restructurings
// (stores-split, rescan, K-split, rotation, LDS-resident codebook) are ALL
// null -> the 200us is invariant to per-block inner work. R5 PMC de-diluted:
// active occupancy ~12% (1 block/CU, half of expected), all pipes <15% busy,
// per-block pre-store path ~14us vs ~2.5us arithmetic. Diagnosis: per-block
// fixed overhead x too-few-resident-blocks (8 serial rounds of ~25us).
// Fix: the per-wave algorithm needs no cross-wave cooperation -> 64-thread
// single-wave blocks, 8192 of them, ~7KB LDS, VGPR<=128 via bounds (64,4):
// up to 16 independent waves/CU (4x), no barrier skew, 4x more blocks to
// amortize fixed overhead. Loss partials via fp32 atomics into 512 bins
// (error ~3e-6 << tolerance; zeroed by prep each iteration).
// ---------------------------------------------------------------------------
__global__ __launch_bounds__(64, 4) void vq_fused(
    const float*          __restrict__ in,    // NCHW [32][64][64][64]
    const float*          __restrict__ emb,   // [512][64] fp32 (recheck+gather)
    const unsigned short* __restrict__ eh,    // frag-order bf16 hi
    const unsigned short* __restrict__ el,    // frag-order bf16 lo
    const float*          __restrict__ nrm,   // [512] ||e||^2 fp32
    unsigned*             __restrict__ hist,  // [512]
    float*                __restrict__ bloss, // [512] atomic bins
    float*                __restrict__ out)
{
    __shared__ float xs[16 * 68];   // [p][d] x-tile, stride 68; reused as qs[16*65]
    __shared__ float nsL[512];
    __shared__ float psxL[64];
    __shared__ float pdistL[16];
    __shared__ int   fidxL[16];
    __shared__ int   flaggedL[16];
    __shared__ int   nflag;
    // ~7 KB

    const int lane = threadIdx.x;        // 64
    const int blk  = blockIdx.x;         // 8192 tiles of 16 points
    const int b    = blk >> 8;           // batch index (256 tiles per batch)
    const int hw0  = (blk & 255) * 16;
    const long inBase = (long)b * (DIMS * HW) + hw0;

    // ---- stage x tile [p][d] + per-(p, d-quarter) sum of squares ----
    {
        const int p  = lane & 15;
        const int dq = lane >> 4;
        float ps = 0.f;
        #pragma unroll
        for (int i = 0; i < 16; i++) {
            int d = dq * 16 + i;
            float v = in[inBase + (long)d * HW + p];
            xs[p * 68 + d] = v;
            ps = fmaf(v, v, ps);
        }
        psxL[lane] = ps;
    }
    // ---- stage codebook norms (8 floats/thread) ----
    {
        const float4* nv = (const float4*)nrm;
        float4 a = nv[lane * 2];
        float4 c = nv[lane * 2 + 1];
        *(float4*)&nsL[lane * 8]     = a;
        *(float4*)&nsL[lane * 8 + 4] = c;
    }
    if (lane == 0) nflag = 0;
    __syncthreads();

    const int col  = lane & 15;
    const int quad = lane >> 4;

    // ---- build A-fragments (16 points, pbase = 0) ----
    short8 ah[2], al[2];
    {
        const float* xrow = &xs[col * 68];
        #pragma unroll
        for (int s = 0; s < 2; s++) {
            int k0 = s * 32 + quad * 8;
            float xv[8];
            *(float4*)&xv[0] = *(const float4*)&xrow[k0];
            *(float4*)&xv[4] = *(const float4*)&xrow[k0 + 4];
            short8 h, lo;
            #pragma unroll
            for (int j = 0; j < 8; j++) {
                unsigned short hb = f2bf(xv[j]);
                h[j]  = (short)hb;
                lo[j] = (short)f2bf(xv[j] - bf2f(hb));
            }
            ah[s] = h; al[s] = lo;
        }
    }

    float b1[4], b2[4];
    int   i1[4];
    #pragma unroll
    for (int r = 0; r < 4; r++) { b1[r] = 1e30f; b2[r] = 1e30f; i1[r] = 0; }

    // ---- t-loop: 512 codes, split-bf16 MFMA distances ----
    {
        const short8* bhF = (const short8*)eh;   // [(t*2+s)*64 + lane]
        const short8* blF = (const short8*)el;
        for (int t = 0; t < 32; t++) {
            short8 bh0 = bhF[(t * 2    ) * 64 + lane];   // coalesced 1 KB/instr
            short8 bh1 = bhF[(t * 2 + 1) * 64 + lane];
            short8 bl0 = blF[(t * 2    ) * 64 + lane];
            short8 bl1 = blF[(t * 2 + 1) * 64 + lane];

            f32x4 acc = {0.f, 0.f, 0.f, 0.f};
            acc = __builtin_amdgcn_mfma_f32_16x16x32_bf16(ah[0], bh0, acc, 0, 0, 0);
            acc = __builtin_amdgcn_mfma_f32_16x16x32_bf16(ah[1], bh1, acc, 0, 0, 0);
            acc = __builtin_amdgcn_mfma_f32_16x16x32_bf16(ah[0], bl0, acc, 0, 0, 0);
            acc = __builtin_amdgcn_mfma_f32_16x16x32_bf16(ah[1], bl1, acc, 0, 0, 0);
            acc = __builtin_amdgcn_mfma_f32_16x16x32_bf16(al[0], bh0, acc, 0, 0, 0);
            acc = __builtin_amdgcn_mfma_f32_16x16x32_bf16(al[1], bh1, acc, 0, 0, 0);

            int   k  = t * 16 + col;
            float nk = nsL[k];
            #pragma unroll
            for (int r = 0; r < 4; r++) {
                float v = fmaf(-2.f, acc[r], nk);   // ||e||^2 - 2 x.e
                bool better = (v < b1[r]);
                b2[r] = better ? b1[r] : fminf(b2[r], v);
                i1[r] = better ? k : i1[r];
                b1[r] = better ? v : b1[r];
            }
        }
    }

    // ---- reduce over 16 code-columns ----
    #pragma unroll
    for (int r = 0; r < 4; r++) {
        float b1v = b1[r], b2v = b2[r];
        int   i1v = i1[r];
        #pragma unroll
        for (int m = 1; m < 16; m <<= 1) {
            float ob1 = __shfl_xor(b1v, m);
            int   oi1 = __shfl_xor(i1v, m);
            float ob2 = __shfl_xor(b2v, m);
            float loser = fmaxf(b1v, ob1);
            b2v = fminf(fminf(b2v, ob2), loser);
            if (ob1 < b1v || (ob1 == b1v && oi1 < i1v)) { b1v = ob1; i1v = oi1; }
        }
        if (col == 0) {
            int p = quad * 4 + r;            // D row = quad*4 + reg
            fidxL[p] = i1v;
            float sx = psxL[p] + psxL[16 + p] + psxL[32 + p] + psxL[48 + p];
            pdistL[p] = sx + b1v;
            if (b2v - b1v < EPS_MARGIN) {
                int s = atomicAdd(&nflag, 1);
                flaggedL[s] = p;
            }
        }
    }
    __syncthreads();

    // ---- wave-local fp64 re-scan for near-tie points (rare) ----
    {
        int nf = nflag;
        for (int f = 0; f < nf; f++) {
            int p = flaggedL[f];
            double bd = 1e300;
            int    bk = 1 << 30;
            #pragma unroll 2
            for (int kk = 0; kk < 8; kk++) {
                int k = (kk << 6) + lane;        // lane's codes: lane, lane+64, ...
                const float4* er = (const float4*)(emb + k * DIMS);
                double s = 0.0;
                #pragma unroll 4
                for (int i = 0; i < 16; i++) {
                    float4 e4 = er[i];
                    double d0 = (double)xs[p * 68 + i * 4    ] - (double)e4.x;
                    double d1 = (double)xs[p * 68 + i * 4 + 1] - (double)e4.y;
                    double d2 = (double)xs[p * 68 + i * 4 + 2] - (double)e4.z;
                    double d3 = (double)xs[p * 68 + i * 4 + 3] - (double)e4.w;
                    s = fma(d0, d0, s); s = fma(d1, d1, s);
                    s = fma(d2, d2, s); s = fma(d3, d3, s);
                }
                if (s < bd || (s == bd && k < bk)) { bd = s; bk = k; }
            }
            #pragma unroll
            for (int off = 32; off > 0; off >>= 1) {
                double ov = __shfl_down(bd, off);
                int    ok = __shfl_down(bk, off);
                if (ov < bd || (ov == bd && ok < bk)) { bd = ov; bk = ok; }
            }
            if (lane == 0) {
                fidxL[p]  = bk;
                pdistL[p] = (float)bd;
            }
        }
    }
    __syncthreads();   // fidx/pdist final before hist + stores

    // ---- histogram + loss partial (fp32 atomic bin) ----
    if (lane < 16) {
        atomicAdd(&hist[fidxL[lane]], 1u);
        float lp = pdistL[lane];
        #pragma unroll
        for (int off = 8; off > 0; off >>= 1)
            lp += __shfl_down(lp, off);
        if (lane == 0) atomicAdd(&bloss[blk & 511], lp);
    }
    __syncthreads();   // all xs reads done before qs overwrite

    // ---- stage chosen embedding rows into qs (aliases xs, stride 65) ----
    float* qs = xs;
    {
        int q = lane & 3, p = lane >> 2;     // 4 threads/row x 16 rows
        int row = fidxL[p];
        const float4* src = (const float4*)(emb + row * DIMS + q * 16);
        #pragma unroll
        for (int i = 0; i < 4; i++) {
            float4 v = src[i];
            int base = p * 65 + q * 16 + i * 4;
            qs[base] = v.x; qs[base + 1] = v.y; qs[base + 2] = v.z; qs[base + 3] = v.w;
        }
    }

    const int n0 = b * HW + hw0;

    // ---- encodings: 16 one-hot rows (needs only fidxL; overlaps staging) ----
    {
        float* encB = out + (long)OFF_ENC + (long)n0 * KCODES;
        #pragma unroll 4
        for (int i = 0; i < 32; i++) {
            int f  = i * 256 + lane * 4;     // 8192 floats
            int p  = f >> 9;
            int k0 = f & 511;
            int fd = fidxL[p];
            f32x4 v;
            v.x = (k0     == fd) ? 1.0f : 0.0f;
            v.y = (k0 + 1 == fd) ? 1.0f : 0.0f;
            v.z = (k0 + 2 == fd) ? 1.0f : 0.0f;
            v.w = (k0 + 3 == fd) ? 1.0f : 0.0f;
            __builtin_nontemporal_store(v, (f32x4*)(encB + f));
        }
    }
    __syncthreads();   // qs staged before transpose reads

    // ---- quantized_flat [n][64] ----
    {
        float* qfB = out + (long)OFF_QF + (long)n0 * DIMS;
        #pragma unroll
        for (int i = 0; i < 4; i++) {
            int f = i * 256 + lane * 4;      // 1024 floats
            int p = f >> 6;
            int d = f & 63;
            f32x4 v;
            v.x = qs[p * 65 + d];     v.y = qs[p * 65 + d + 1];
            v.z = qs[p * 65 + d + 2]; v.w = qs[p * 65 + d + 3];
            __builtin_nontemporal_store(v, (f32x4*)(qfB + f));
        }
    }

    // ---- quantized_out NCHW: 64 rows x 16 floats ----
    {
        float* qoB = out + (long)OFF_QOUT + (long)b * (DIMS * HW) + hw0;
        #pragma unroll
        for (int i = 0; i < 4; i++) {
            int f4  = i * 64 + lane;         // 256 float4
            int d   = f4 >> 2;               // row 0..63
            int seg = f4 & 3;                // float4 segment within 16
            f32x4 v;
            v.x = qs[(seg * 4    ) * 65 + d];
            v.y = qs[(seg * 4 + 1) * 65 + d];
            v.z = qs[(seg * 4 + 2) * 65 + d];
            v.w = qs[(seg * 4 + 3) * 65 + d];
            __builtin_nontemporal_store(v, (f32x4*)(qoB + (long)d * HW + seg * 4));
        }
    }
}

// ---------------------------------------------------------------------------
// Finalize: loss scalar + perplexity (fp64)
// ---------------------------------------------------------------------------
__global__ void vq_finalize(const unsigned* __restrict__ hist,
                            const float* __restrict__ bloss,
                            float* __restrict__ out)
{
    __shared__ double sl[512];
    __shared__ double sh[512];
    int tid = threadIdx.x;   // 512

    double l = (double)bloss[tid];

    unsigned c = hist[tid];
    double p = (double)c * (1.0 / 131072.0);
    double h = p * log(p + 1e-10);

    sl[tid] = l;
    sh[tid] = h;
    __syncthreads();
    for (int s = 256; s > 0; s >>= 1) {
        if (tid < s) { sl[tid] += sl[tid + s]; sh[tid] += sh[tid + s]; }
        __syncthreads();
    }
    if (tid == 0) {
        out[OFF_LOSS] = (float)(0.25 * sl[0] / 8388608.0);
        out[OFF_PERP] = (float)exp(-sh[0]);
    }
}

// ---------------------------------------------------------------------------
extern "C" void kernel_launch(void* const* d_in, const int* in_sizes, int n_in,
                              void* d_out, int out_size, void* d_ws, size_t ws_size,
                              hipStream_t stream)
{
    const float* in  = (const float*)d_in[0];   // inputs  [32,64,64,64] f32
    const float* emb = (const float*)d_in[1];   // codebook [512,64] f32
    float* out = (float*)d_out;
    char*  ws  = (char*)d_ws;

    unsigned*       hist  = (unsigned*)      (ws + WS_HIST);
    float*          nrm   = (float*)         (ws + WS_NRM);
    unsigned short* eh    = (unsigned short*)(ws + WS_EH);
    unsigned short* el    = (unsigned short*)(ws + WS_EL);
    float*          bloss = (float*)         (ws + WS_BLOSS);

    vq_prep<<<KCODES, 64, 0, stream>>>(emb, eh, el, nrm, hist, bloss);
    vq_fused<<<NPTS / 16, 64, 0, stream>>>(in, emb, eh, el, nrm, hist, bloss, out);
    vq_finalize<<<1, 512, 0, stream>>>(hist, bloss, out);
}

// Round 10
// 482.026 us; speedup vs baseline: 1.0345x; 1.0345x over previous
//
#include <hip/hip_runtime.h>
#include <math.h>

// Problem constants
#define NPTS   131072          // 32*64*64 points
#define DIMS   64              // embedding dim / channels
#define KCODES 512             // codebook size
#define HW     4096            // 64*64 spatial

// d_out flat offsets (floats), reference tuple order:
// (loss, quantized_out[NCHW], perplexity, encodings, quantized_flat)
#define OFF_LOSS 0
#define OFF_QOUT 1
#define OFF_PERP 8388609
#define OFF_ENC  8388610
#define OFF_QF   75497474   // 8388610 + 67108864

// d_ws byte offsets (R3 layout)
#define WS_HIST  0          // unsigned[512]  (zeroed by vq_prep)
#define WS_BLOSS 2048       // float[2048]
#define WS_NRM   10240      // float[512]
#define WS_EH    12288      // ushort[512*64] bf16 hi, MFMA-fragment order
#define WS_EL    77824      // ushort[512*64] bf16 lo, MFMA-fragment order

// split-bf16 distance error <~2.4e-4; pairwise comparison error <4.8e-4.
// margin 2e-3 still flags every possible argmin flip (4x cushion).
#define EPS_MARGIN 2e-3f

typedef __attribute__((ext_vector_type(8))) short short8;
typedef __attribute__((ext_vector_type(4))) float f32x4;

__device__ __forceinline__ unsigned short f2bf(float f) {
    unsigned u = __float_as_uint(f);
    unsigned r = (u + 0x7fffu + ((u >> 16) & 1u)) >> 16;   // RNE
    return (unsigned short)r;
}
__device__ __forceinline__ float bf2f(unsigned short h) {
    return __uint_as_float(((unsigned)h) << 16);
}

// ---------------------------------------------------------------------------
// Prep: split codebook into bf16 hi/lo in MFMA B-fragment order (see R3).
// Also zeroes hist.
// ---------------------------------------------------------------------------
__global__ void vq_prep(const float* __restrict__ emb,
                        unsigned short* __restrict__ ehF,
                        unsigned short* __restrict__ elF,
                        float* __restrict__ nrm,
                        unsigned* __restrict__ hist)
{
    int k = blockIdx.x;      // 512
    int d = threadIdx.x;     // 64
    float v = emb[k * DIMS + d];
    unsigned short h = f2bf(v);
    int t = k >> 4, col = k & 15;
    int s = d >> 5, quad = (d >> 3) & 3, j = d & 7;
    int idx = (((t * 2 + s) * 64) + quad * 16 + col) * 8 + j;
    ehF[idx] = h;
    elF[idx] = f2bf(v - bf2f(h));
    double sq = (double)v * (double)v;
    #pragma unroll
    for (int off = 32; off > 0; off >>= 1)
        sq += __shfl_down(sq, off, 64);
    if (d == 0) { nrm[k] = (float)sq; hist[k] = 0u; }
}

// ---------------------------------------------------------------------------
// ROUND-10: SINGLE-WAVE, FULL-TILE (64 points/wave). R9 evidence: 3x more
// resident waves -> same duration (per-wave 3x slower): a shared resource
// saturates at <=4 waves/CU while VALU 12% / MFMA 4% / LDS / HBM all idle.
// The quantity invariant across both ~200us cores (R3, R9) is the 128KB
// codebook stream PER WAVE. This round: 2048 independent single-wave blocks,
// each with A-frags for all 4 point-groups in VGPRs -> codebook bytes/point
// / 4, waves chip-wide / 4, 24 MFMAs per 4 B-loads (6x latency cover), no
// inter-wave barriers, and R3's memory-efficient 64-float rows (fixes R9's
// FETCH 250MB / WRITE 540MB regression).
// __launch_bounds__(64,2): VGPR cap 256 (est ~170, no spill).
// ---------------------------------------------------------------------------
__global__ __launch_bounds__(64, 2) void vq_fused(
    const float*          __restrict__ in,    // NCHW [32][64][64][64]
    const float*          __restrict__ emb,   // [512][64] fp32 (recheck+gather)
    const unsigned short* __restrict__ eh,    // frag-order bf16 hi
    const unsigned short* __restrict__ el,    // frag-order bf16 lo
    const float*          __restrict__ nrm,   // [512] ||e||^2 fp32
    unsigned*             __restrict__ hist,  // [512]
    float*                __restrict__ bloss, // [2048]
    float*                __restrict__ out)
{
    __shared__ float xs[64 * 68];   // [p][d] x-tile, stride 68 (17.4 KB); reused as qs
    __shared__ float nsL[512];
    __shared__ float psxL[64];
    __shared__ float pdistL[64];
    __shared__ int   fidxL[64];
    __shared__ int   flaggedL[64];
    __shared__ int   nflag;
    // ~20 KB

    const int lane = threadIdx.x;        // 64
    const int blk  = blockIdx.x;         // 2048 tiles of 64 points
    const int b    = blk >> 6;
    const int hw0  = (blk & 63) * 64;
    const long inBase = (long)b * (DIMS * HW) + hw0;

    // ---- stage x tile [p][d]: thread lane owns point lane (coalesced per d) ----
    {
        float ps = 0.f;
        #pragma unroll 8
        for (int d = 0; d < 64; d++) {
            float v = in[inBase + (long)d * HW + lane];
            xs[lane * 68 + d] = v;
            ps = fmaf(v, v, ps);
        }
        psxL[lane] = ps;
    }
    // ---- stage codebook norms (8 floats/thread) ----
    {
        const float4* nv = (const float4*)nrm;
        float4 a = nv[lane * 2];
        float4 c = nv[lane * 2 + 1];
        *(float4*)&nsL[lane * 8]     = a;
        *(float4*)&nsL[lane * 8 + 4] = c;
    }
    if (lane == 0) nflag = 0;
    __syncthreads();

    const int col  = lane & 15;
    const int quad = lane >> 4;

    // ---- A-fragments for ALL 4 point-groups ----
    short8 ah[4][2], al[4][2];
    #pragma unroll
    for (int pg = 0; pg < 4; pg++) {
        const float* xrow = &xs[(pg * 16 + col) * 68];
        #pragma unroll
        for (int s = 0; s < 2; s++) {
            int k0 = s * 32 + quad * 8;
            float xv[8];
            *(float4*)&xv[0] = *(const float4*)&xrow[k0];
            *(float4*)&xv[4] = *(const float4*)&xrow[k0 + 4];
            short8 h, lo;
            #pragma unroll
            for (int j = 0; j < 8; j++) {
                unsigned short hb = f2bf(xv[j]);
                h[j]  = (short)hb;
                lo[j] = (short)f2bf(xv[j] - bf2f(hb));
            }
            ah[pg][s] = h; al[pg][s] = lo;
        }
    }

    float b1[4][4], b2[4][4];
    int   i1[4][4];
    #pragma unroll
    for (int pg = 0; pg < 4; pg++)
        #pragma unroll
        for (int r = 0; r < 4; r++) { b1[pg][r] = 1e30f; b2[pg][r] = 1e30f; i1[pg][r] = 0; }

    // ---- t-loop: 512 codes; 4 loads feed 24 MFMAs ----
    {
        const short8* bhF = (const short8*)eh;   // [(t*2+s)*64 + lane]
        const short8* blF = (const short8*)el;
        for (int t = 0; t < 32; t++) {
            short8 bh0 = bhF[(t * 2    ) * 64 + lane];   // coalesced 1 KB/instr
            short8 bh1 = bhF[(t * 2 + 1) * 64 + lane];
            short8 bl0 = blF[(t * 2    ) * 64 + lane];
            short8 bl1 = blF[(t * 2 + 1) * 64 + lane];

            const int   k  = t * 16 + col;
            const float nk = nsL[k];

            #pragma unroll
            for (int pg = 0; pg < 4; pg++) {
                f32x4 acc = {0.f, 0.f, 0.f, 0.f};
                acc = __builtin_amdgcn_mfma_f32_16x16x32_bf16(ah[pg][0], bh0, acc, 0, 0, 0);
                acc = __builtin_amdgcn_mfma_f32_16x16x32_bf16(ah[pg][1], bh1, acc, 0, 0, 0);
                acc = __builtin_amdgcn_mfma_f32_16x16x32_bf16(ah[pg][0], bl0, acc, 0, 0, 0);
                acc = __builtin_amdgcn_mfma_f32_16x16x32_bf16(ah[pg][1], bl1, acc, 0, 0, 0);
                acc = __builtin_amdgcn_mfma_f32_16x16x32_bf16(al[pg][0], bh0, acc, 0, 0, 0);
                acc = __builtin_amdgcn_mfma_f32_16x16x32_bf16(al[pg][1], bh1, acc, 0, 0, 0);

                #pragma unroll
                for (int r = 0; r < 4; r++) {
                    float v = fmaf(-2.f, acc[r], nk);   // ||e||^2 - 2 x.e
                    bool better = (v < b1[pg][r]);
                    b2[pg][r] = better ? b1[pg][r] : fminf(b2[pg][r], v);
                    i1[pg][r] = better ? k : i1[pg][r];
                    b1[pg][r] = better ? v : b1[pg][r];
                }
            }
        }
    }

    // ---- reduce over 16 code-columns ----
    #pragma unroll
    for (int pg = 0; pg < 4; pg++) {
        #pragma unroll
        for (int r = 0; r < 4; r++) {
            float b1v = b1[pg][r], b2v = b2[pg][r];
            int   i1v = i1[pg][r];
            #pragma unroll
            for (int m = 1; m < 16; m <<= 1) {
                float ob1 = __shfl_xor(b1v, m);
                int   oi1 = __shfl_xor(i1v, m);
                float ob2 = __shfl_xor(b2v, m);
                float loser = fmaxf(b1v, ob1);
                b2v = fminf(fminf(b2v, ob2), loser);
                if (ob1 < b1v || (ob1 == b1v && oi1 < i1v)) { b1v = ob1; i1v = oi1; }
            }
            if (col == 0) {
                int p = pg * 16 + quad * 4 + r;   // D row = quad*4 + reg
                fidxL[p] = i1v;
                pdistL[p] = psxL[p] + b1v;
                if (b2v - b1v < EPS_MARGIN) {
                    int s = atomicAdd(&nflag, 1);
                    flaggedL[s] = p;
                }
            }
        }
    }
    __syncthreads();

    // ---- wave fp64 re-scan for near-tie points (rare) ----
    {
        int nf = nflag;
        for (int f = 0; f < nf; f++) {
            int p = flaggedL[f];
            double bd = 1e300;
            int    bk = 1 << 30;
            #pragma unroll 2
            for (int kk = 0; kk < 8; kk++) {
                int k = (kk << 6) + lane;        // lane's codes: lane, lane+64, ...
                const float4* er = (const float4*)(emb + k * DIMS);
                double s = 0.0;
                #pragma unroll 4
                for (int i = 0; i < 16; i++) {
                    float4 e4 = er[i];
                    double d0 = (double)xs[p * 68 + i * 4    ] - (double)e4.x;
                    double d1 = (double)xs[p * 68 + i * 4 + 1] - (double)e4.y;
                    double d2 = (double)xs[p * 68 + i * 4 + 2] - (double)e4.z;
                    double d3 = (double)xs[p * 68 + i * 4 + 3] - (double)e4.w;
                    s = fma(d0, d0, s); s = fma(d1, d1, s);
                    s = fma(d2, d2, s); s = fma(d3, d3, s);
                }
                if (s < bd || (s == bd && k < bk)) { bd = s; bk = k; }
            }
            #pragma unroll
            for (int off = 32; off > 0; off >>= 1) {
                double ov = __shfl_down(bd, off);
                int    ok = __shfl_down(bk, off);
                if (ov < bd || (ov == bd && ok < bk)) { bd = ov; bk = ok; }
            }
            if (lane == 0) {
                fidxL[p]  = bk;
                pdistL[p] = (float)bd;
            }
        }
    }
    __syncthreads();   // fidx/pdist final before hist + stores

    // ---- histogram + loss partial ----
    {
        atomicAdd(&hist[fidxL[lane]], 1u);
        float lp = pdistL[lane];
        #pragma unroll
        for (int off = 32; off > 0; off >>= 1)
            lp += __shfl_down(lp, off);
        if (lane == 0) bloss[blk] = lp;
    }
    __syncthreads();   // all xs reads done before qs overwrite

    // ---- stage chosen embedding rows into qs (aliases xs, stride 65) ----
    float* qs = xs;
    {
        #pragma unroll
        for (int g = 0; g < 4; g++) {
            int vt = g * 64 + lane;
            int q = vt & 3, p = vt >> 2;
            int row = fidxL[p];
            const float4* src = (const float4*)(emb + row * DIMS + q * 16);
            #pragma unroll
            for (int i = 0; i < 4; i++) {
                float4 v = src[i];
                int base = p * 65 + q * 16 + i * 4;
                qs[base] = v.x; qs[base + 1] = v.y; qs[base + 2] = v.z; qs[base + 3] = v.w;
            }
        }
    }

    const int n0 = b * HW + hw0;

    // ---- encodings: 64 one-hot rows (needs only fidxL; overlaps staging) ----
    {
        float* encB = out + (long)OFF_ENC + (long)n0 * KCODES;
        #pragma unroll 4
        for (int i = 0; i < 128; i++) {
            int f  = i * 256 + lane * 4;     // 32768 floats
            int p  = f >> 9;
            int k0 = f & 511;
            int fd = fidxL[p];
            f32x4 v;
            v.x = (k0     == fd) ? 1.0f : 0.0f;
            v.y = (k0 + 1 == fd) ? 1.0f : 0.0f;
            v.z = (k0 + 2 == fd) ? 1.0f : 0.0f;
            v.w = (k0 + 3 == fd) ? 1.0f : 0.0f;
            __builtin_nontemporal_store(v, (f32x4*)(encB + f));
        }
    }
    __syncthreads();   // qs staged before transpose reads

    // ---- quantized_flat [n][64] ----
    {
        float* qfB = out + (long)OFF_QF + (long)n0 * DIMS;
        #pragma unroll
        for (int i = 0; i < 16; i++) {
            int f = i * 256 + lane * 4;      // 4096 floats
            int p = f >> 6;
            int d = f & 63;
            f32x4 v;
            v.x = qs[p * 65 + d];     v.y = qs[p * 65 + d + 1];
            v.z = qs[p * 65 + d + 2]; v.w = qs[p * 65 + d + 3];
            __builtin_nontemporal_store(v, (f32x4*)(qfB + f));
        }
    }

    // ---- quantized_out NCHW: 1024 float4 per block ----
    {
        float* qoB = out + (long)OFF_QOUT + (long)b * (DIMS * HW) + hw0;
        #pragma unroll
        for (int i = 0; i < 16; i++) {
            int f4  = i * 64 + lane;         // 1024 float4
            int d   = f4 >> 4;               // row 0..63
            int seg = f4 & 15;               // float4 segment within row
            f32x4 v;
            v.x = qs[(seg * 4    ) * 65 + d];
            v.y = qs[(seg * 4 + 1) * 65 + d];
            v.z = qs[(seg * 4 + 2) * 65 + d];
            v.w = qs[(seg * 4 + 3) * 65 + d];
            __builtin_nontemporal_store(v, (f32x4*)(qoB + (long)d * HW + seg * 4));
        }
    }
}

// ---------------------------------------------------------------------------
// Finalize: loss scalar + perplexity (fp64)
// ---------------------------------------------------------------------------
__global__ void vq_finalize(const unsigned* __restrict__ hist,
                            const float* __restrict__ bloss,
                            float* __restrict__ out)
{
    __shared__ double sl[512];
    __shared__ double sh[512];
    int tid = threadIdx.x;   // 512

    double l = (double)bloss[tid] + (double)bloss[tid + 512]
             + (double)bloss[tid + 1024] + (double)bloss[tid + 1536];

    unsigned c = hist[tid];
    double p = (double)c * (1.0 / 131072.0);
    double h = p * log(p + 1e-10);

    sl[tid] = l;
    sh[tid] = h;
    __syncthreads();
    for (int s = 256; s > 0; s >>= 1) {
        if (tid < s) { sl[tid] += sl[tid + s]; sh[tid] += sh[tid + s]; }
        __syncthreads();
    }
    if (tid == 0) {
        out[OFF_LOSS] = (float)(0.25 * sl[0] / 8388608.0);
        out[OFF_PERP] = (float)exp(-sh[0]);
    }
}

// ---------------------------------------------------------------------------
extern "C" void kernel_launch(void* const* d_in, const int* in_sizes, int n_in,
                              void* d_out, int out_size, void* d_ws, size_t ws_size,
                              hipStream_t stream)
{
    const float* in  = (const float*)d_in[0];   // inputs  [32,64,64,64] f32
    const float* emb = (const float*)d_in[1];   // codebook [512,64] f32
    float* out = (float*)d_out;
    char*  ws  = (char*)d_ws;

    unsigned*       hist  = (unsigned*)      (ws + WS_HIST);
    float*          bloss = (float*)         (ws + WS_BLOSS);
    float*          nrm   = (float*)         (ws + WS_NRM);
    unsigned short* eh    = (unsigned short*)(ws + WS_EH);
    unsigned short* el    = (unsigned short*)(ws + WS_EL);

    vq_prep<<<KCODES, 64, 0, stream>>>(emb, eh, el, nrm, hist);
    vq_fused<<<2048, 64, 0, stream>>>(in, emb, eh, el, nrm, hist, bloss, out);
    vq_finalize<<<1, 512, 0, stream>>>(hist, bloss, out);
}